// Round 19
// baseline (46.598 us; speedup 1.0000x reference)
//
#include <hip/hip_runtime.h>
#include <hip/hip_bf16.h>
#include <hip/hip_fp16.h>

// Self-attention: B=4, N=4096 (64x64 spatial), C=256, D=32.
//   proj_kernel  : MFMA GEMM (~2.5us, validated). k,q row-major [B*N][32] f16
//                  (q pre-scaled by log2e); v packed per-consumer-lane f16:
//                  vT3[gtile][lane][16B], lane=(g<<4)|q holds {V[q][4k],V[16+q][4k]}.
//   attn_partial : grid 1024 = 32 qb(128 rows) x 4 b x 8 ks -> 4 blocks/CU =
//                  8 waves/SIMD = 100% occupancy ceiling (R17 tested 4 waves/SIMD:
//                  no change vs 2 -> this is the last untested occupancy cell,
//                  now with lean ~55-VGPR state that fits the 64-VGPR allocation).
//                  Wave = ONE q-tile x 512 k. K/V streamed through LDS in 4
//                  chunks of 128 k, double-buffered, reg-staged (R15/R17 pattern).
//   attn_combine : exact softmax merge of 8 k-split partials + MFMA Wo-epilogue
//                  (Wo^T in LDS) + gamma*(..)+x residual.

#define BB 4
#define NN 4096
#define CC 256
#define DD 32
#define LOG2E 1.44269504088896340736f
#define THR2 11.0f
#define NROW (BB * NN)      // 16384
#define KSPLIT 8
#define NCH 4               // chunks of 128 k per block (8 k-tiles each)

typedef _Float16 half_t;
typedef _Float16 half2_t __attribute__((ext_vector_type(2)));
typedef _Float16 half4_t __attribute__((ext_vector_type(4)));
typedef _Float16 half8_t __attribute__((ext_vector_type(8)));
typedef float f32x4 __attribute__((ext_vector_type(4)));

#define MFMA_QK(a, b, c) __builtin_amdgcn_mfma_f32_16x16x32_f16(a, b, c, 0, 0, 0)
#define MFMA_PV(a, b, c) __builtin_amdgcn_mfma_f32_16x16x16f16(a, b, c, 0, 0, 0)

static __device__ inline float fexp2(float x) {
#if __has_builtin(__builtin_amdgcn_exp2f)
    return __builtin_amdgcn_exp2f(x);
#else
    return exp2f(x);
#endif
}

// pack two f32 -> 2x f16 (v_cvt_pkrtz_f16_f32), with explicit type bridge
static __device__ __forceinline__ half2_t pk_f16(float a, float b) {
    auto r = __builtin_amdgcn_cvt_pkrtz(a, b);   // __fp16 ext_vector(2)
    return *reinterpret_cast<half2_t*>(&r);
}

// ---------------- Kernel 1: fused QKV projection (MFMA) ----------------
// grid 256 blocks x 512 threads (8 waves); block = 64 rows of x. XCD-pinned.
__global__ __launch_bounds__(512) void proj_kernel(
    const float* __restrict__ x,
    const float* __restrict__ Wk, const float* __restrict__ bk,
    const float* __restrict__ Wq, const float* __restrict__ bq,
    const float* __restrict__ Wv, const float* __restrict__ bv,
    half_t* __restrict__ k_ws, half_t* __restrict__ q_ws, half_t* __restrict__ vT3)
{
    __shared__ half_t xs16[64][264];  // x tile f16 (rows 16B-aligned)
    __shared__ half_t Wt[96][264];    // [Wk|Wq|Wv]^T : Wt[wcol][kdim]

    const int t = threadIdx.x;
    const int xcd = blockIdx.x & 7, slot = blockIdx.x >> 3;
    const int bb = xcd >> 1;                      // batch 0..3
    const int c64 = (slot << 1) | (xcd & 1);      // chunk 0..63
    const int row0 = bb * NN + c64 * 64;

    // stage x tile [64][256] fp32 -> f16
    const float4* x4 = reinterpret_cast<const float4*>(x) + (size_t)row0 * 64;
    for (int idx = t; idx < 64 * 64; idx += 512) {
        int r = idx >> 6, c4 = idx & 63;
        float4 v = x4[r * 64 + c4];
        half4_t h;
        h[0] = (half_t)v.x; h[1] = (half_t)v.y; h[2] = (half_t)v.z; h[3] = (half_t)v.w;
        *reinterpret_cast<half4_t*>(&xs16[r][c4 * 4]) = h;
    }

    // stage W^T (q columns pre-scaled by log2e)
    for (int idx = t; idx < 3072; idx += 512) {
        int cp = idx & 127;           // c-pair
        int rest = idx >> 7;          // 0..23
        int d4 = (rest & 7) * 4;
        int mat = rest >> 3;          // 0:k 1:q 2:v
        const float* Wm = (mat == 0) ? Wk : ((mat == 1) ? Wq : Wv);
        const float sc = (mat == 1) ? LOG2E : 1.0f;
        float4 w0 = *reinterpret_cast<const float4*>(Wm + (2 * cp) * DD + d4);
        float4 w1 = *reinterpret_cast<const float4*>(Wm + (2 * cp + 1) * DD + d4);
        int rbase = mat * 32 + d4;
        half2_t h;
        h[0] = (half_t)(w0.x * sc); h[1] = (half_t)(w1.x * sc);
        *reinterpret_cast<half2_t*>(&Wt[rbase + 0][2 * cp]) = h;
        h[0] = (half_t)(w0.y * sc); h[1] = (half_t)(w1.y * sc);
        *reinterpret_cast<half2_t*>(&Wt[rbase + 1][2 * cp]) = h;
        h[0] = (half_t)(w0.z * sc); h[1] = (half_t)(w1.z * sc);
        *reinterpret_cast<half2_t*>(&Wt[rbase + 2][2 * cp]) = h;
        h[0] = (half_t)(w0.w * sc); h[1] = (half_t)(w1.w * sc);
        *reinterpret_cast<half2_t*>(&Wt[rbase + 3][2 * cp]) = h;
    }
    __syncthreads();

    const int w = t >> 6, lane = t & 63;
    const int c = lane & 15, g = lane >> 4;
    const int rt = w >> 1;            // row tile 0..3
    const int ct0 = (w & 1) * 3;      // col tiles ct0..ct0+2

    f32x4 acc[3];
#pragma unroll
    for (int j = 0; j < 3; ++j) acc[j] = (f32x4){0.f, 0.f, 0.f, 0.f};

#pragma unroll
    for (int kk = 0; kk < 8; ++kk) {
        const int k0 = kk * 32 + g * 8;
        half8_t bfrag = *reinterpret_cast<const half8_t*>(&xs16[rt * 16 + c][k0]);
#pragma unroll
        for (int j = 0; j < 3; ++j) {
            half8_t afrag = *reinterpret_cast<const half8_t*>(&Wt[(ct0 + j) * 16 + c][k0]);
            acc[j] = MFMA_QK(afrag, bfrag, acc[j]);
        }
    }

    // store: lane holds C[xrow = rt*16+c][wcol = ct*16+4g+i]
    const int grow = row0 + rt * 16 + c;
#pragma unroll
    for (int j = 0; j < 3; ++j) {
        const int ct = ct0 + j;
        const int mat = ct >> 1;           // 0:k 1:q 2:v
        const float* bm = (mat == 0) ? bk : ((mat == 1) ? bq : bv);
        float4 bb4 = *reinterpret_cast<const float4*>(bm + (ct & 1) * 16 + g * 4);
        const int d0 = (ct & 1) * 16 + g * 4;
        if (mat < 2) {
            const float bsc = (mat == 1) ? LOG2E : 1.0f;
            half_t* dst = (mat == 0) ? k_ws : q_ws;
            half4_t h;
            h[0] = (half_t)(acc[j][0] + bb4.x * bsc);
            h[1] = (half_t)(acc[j][1] + bb4.y * bsc);
            h[2] = (half_t)(acc[j][2] + bb4.z * bsc);
            h[3] = (half_t)(acc[j][3] + bb4.w * bsc);
            *reinterpret_cast<half4_t*>(dst + (size_t)grow * DD + d0) = h;
        } else {
            // vT3 packed f16: gtile = grow>>4, kk' = grow&15 == c.
            // half index: l = (kk'>>2)*16 + (d&15); h = l*8 + (d>=16?4:0) + (kk'&3)
            const size_t tbase = (size_t)(grow >> 4) * 512;
            float vals[4] = {acc[j][0] + bb4.x, acc[j][1] + bb4.y,
                             acc[j][2] + bb4.z, acc[j][3] + bb4.w};
#pragma unroll
            for (int i = 0; i < 4; ++i) {
                int d = d0 + i;
                int l = ((c >> 2) << 4) | (d & 15);
                int h = l * 8 + ((d >> 4) << 2) + (c & 3);
                vT3[tbase + h] = (half_t)vals[i];
            }
        }
    }
}

// ---------------- Kernel 2: q-split/k-split flash attention partial ----------------
// grid 1024 x 512 threads (8 waves), 4 blocks/CU -> 8 waves/SIMD (full occupancy).
// Block = 128 q-rows x 512 k (k-eighth ks). Wave w owns q-tile w.
// K/V streamed via LDS in 4 double-buffered chunks of 8 k-tiles (128 k).
__global__ __launch_bounds__(512) void attn_partial(
    const half_t* __restrict__ k_ws, const half_t* __restrict__ q_ws,
    const half_t* __restrict__ vT3,
    float* __restrict__ pm, float* __restrict__ ps, float* __restrict__ pO)
{
    __shared__ half_t kbuf[2][8][512];   // 16 KB: [buf][ktile][lane-major 16B frags]
    __shared__ half_t vbuf[2][8][512];   // 16 KB

    const int tid = threadIdx.x;
    const int w = tid >> 6, lane = tid & 63;
    const int q = lane & 15, g = lane >> 4;
    // XCD pinning: batch -> XCD pair
    const int xcd = blockIdx.x & 7, rest = blockIdx.x >> 3;
    const int b = xcd >> 1;
    const int u = (rest << 1) | (xcd & 1);   // 0..255
    const int qb = u >> 3;                   // 0..31 (128-row block)
    const int ks = u & 7;                    // k eighth
    const int r0 = b * NN + qb * 128;

    // Q fragment for this wave's q-tile (pre-scaled by log2e)
    half8_t qf = *reinterpret_cast<const half8_t*>(
        q_ws + (size_t)(r0 + w * 16 + q) * DD + g * 8);

    float m = -3.0e38f, ss = 0.f;
    f32x4 acc0 = {0.f, 0.f, 0.f, 0.f};   // d = 4g+i
    f32x4 acc1 = {0.f, 0.f, 0.f, 0.f};   // d = 16+4g+i

    const int t0 = ks * 32;              // k-tile base within batch (32 tiles = 512 k)
    // staging sources for wave w (one K tile + one V tile per chunk)
    const half_t* ksrc = k_ws + ((size_t)b * NN + q) * DD + g * 8;  // + tile*16*DD
    const half_t* vsrc = vT3 + (size_t)lane * 8;                    // + gtile*512

    // prologue: stage chunk 0 (wave w stages local tile w)
    {
        half8_t sK = *reinterpret_cast<const half8_t*>(ksrc + (size_t)(t0 + w) * 16 * DD);
        half8_t sV = *reinterpret_cast<const half8_t*>(vsrc + (size_t)(b * 256 + t0 + w) * 512);
        *reinterpret_cast<half8_t*>(&kbuf[0][w][lane * 8]) = sK;
        *reinterpret_cast<half8_t*>(&vbuf[0][w][lane * 8]) = sV;
    }
    __syncthreads();

    for (int ch = 0; ch < NCH; ++ch) {
        const int cb = ch & 1;

        // issue next chunk's loads now (ds_write happens after this chunk's compute)
        half8_t sK, sV;
        if (ch + 1 < NCH) {
            const int lt = t0 + (ch + 1) * 8 + w;
            sK = *reinterpret_cast<const half8_t*>(ksrc + (size_t)lt * 16 * DD);
            sV = *reinterpret_cast<const half8_t*>(vsrc + (size_t)(b * 256 + lt) * 512);
        }

        // compute 8 k-tiles from buf[cb]
#pragma unroll
        for (int t = 0; t < 8; ++t) {
            half8_t kf = *reinterpret_cast<const half8_t*>(&kbuf[cb][t][lane * 8]);
            half8_t vv = *reinterpret_cast<const half8_t*>(&vbuf[cb][t][lane * 8]);

            f32x4 z = {0.f, 0.f, 0.f, 0.f};
            f32x4 s = MFMA_QK(kf, qf, z);

            float tmax = fmaxf(fmaxf(s[0], s[1]), fmaxf(s[2], s[3]));
            if (!__all(tmax <= m + THR2)) {
                float rmax = fmaxf(tmax, __shfl_xor(tmax, 16));
                rmax = fmaxf(rmax, __shfl_xor(rmax, 32));
                float mn = fmaxf(m, rmax);
                float sc = fexp2(m - mn);
                ss *= sc;
                acc0 *= sc;
                acc1 *= sc;
                m = mn;
            }

            float p0 = fexp2(s[0] - m), p1 = fexp2(s[1] - m);
            float p2 = fexp2(s[2] - m), p3 = fexp2(s[3] - m);
            ss += (p0 + p1) + (p2 + p3);

            half2_t pa = pk_f16(p0, p1);
            half2_t pb = pk_f16(p2, p3);
            half4_t pf;
            pf[0] = pa[0]; pf[1] = pa[1]; pf[2] = pb[0]; pf[3] = pb[1];

            half4_t va0 = __builtin_shufflevector(vv, vv, 0, 1, 2, 3);
            half4_t va1 = __builtin_shufflevector(vv, vv, 4, 5, 6, 7);

            acc0 = MFMA_PV(va0, pf, acc0);
            acc1 = MFMA_PV(va1, pf, acc1);
        }

        // write next chunk into the other buffer, then one barrier
        if (ch + 1 < NCH) {
            *reinterpret_cast<half8_t*>(&kbuf[cb ^ 1][w][lane * 8]) = sK;
            *reinterpret_cast<half8_t*>(&vbuf[cb ^ 1][w][lane * 8]) = sV;
        }
        __syncthreads();
    }

    // fold lane-local ss to row sum
    ss += __shfl_xor(ss, 16);
    ss += __shfl_xor(ss, 32);

    // write partials: pm/ps per row; pO[(ks*NROW + r)*32 + d]
    if (lane < 16) {
        pm[(size_t)ks * NROW + r0 + w * 16 + lane] = m;
        ps[(size_t)ks * NROW + r0 + w * 16 + lane] = ss;
    }
    {
        const int r = r0 + w * 16 + q;
        float* po = pO + ((size_t)ks * NROW + r) * 32;
        *reinterpret_cast<f32x4*>(po + g * 4) = acc0;
        *reinterpret_cast<f32x4*>(po + 16 + g * 4) = acc1;
    }
}

// ---------------- Kernel 3: combine + output projection ----------------
// grid 256 blocks (b*64+qb) x 512 threads. Block = 64 q-rows.
__global__ __launch_bounds__(512) void attn_combine(
    const float* __restrict__ pm, const float* __restrict__ ps,
    const float* __restrict__ pO,
    const float* __restrict__ x, const float* __restrict__ Wo,
    const float* __restrict__ bo, const float* __restrict__ gamma,
    float* __restrict__ out)
{
    __shared__ half_t feat_h[64 * 40];    // 5 KB
    __shared__ half_t woT[256 * 40];      // 20 KB Wo^T f16: woT[c*40+d]

    const int tid = threadIdx.x;
    const int b = blockIdx.x >> 6, qb = blockIdx.x & 63;
    const int q0 = qb * 64;
    const int r0 = b * NN + q0;

    // stage Wo^T as f16
#pragma unroll
    for (int it = 0; it < 16; ++it) {
        int idx = tid + it * 512;
        int c = idx & 255, d = idx >> 8;
        woT[c * 40 + d] = (half_t)Wo[d * CC + c];
    }

    // exact softmax merge of 8 k-split partials: thread -> (r = tid>>3, d4 = (tid&7)*4)
    {
        const int r = tid >> 3, d4 = (tid & 7) * 4;
        const int gr = r0 + r;
        float mv[KSPLIT];
        float M = -3.0e38f;
#pragma unroll
        for (int k = 0; k < KSPLIT; ++k) {
            mv[k] = pm[(size_t)k * NROW + gr];
            M = fmaxf(M, mv[k]);
        }
        float S = 0.f;
        f32x4 f = {0.f, 0.f, 0.f, 0.f};
#pragma unroll
        for (int k = 0; k < KSPLIT; ++k) {
            float wgt = fexp2(mv[k] - M);
            S += ps[(size_t)k * NROW + gr] * wgt;
            f32x4 p = *reinterpret_cast<const f32x4*>(pO + ((size_t)k * NROW + gr) * 32 + d4);
            f += p * wgt;
        }
        float inv = 1.0f / S;
#pragma unroll
        for (int i = 0; i < 4; ++i) feat_h[r * 40 + d4 + i] = (half_t)(f[i] * inv);
    }
    __syncthreads();

    // MFMA epilogue: O[r][c] = gamma*(feat@Wo + bo) + x  (validated structure)
    const int w = tid >> 6, lane = tid & 63;
    const int q = lane & 15, g = lane >> 4;
    const float gam = gamma[0];
#pragma unroll
    for (int j = 0; j < 2; ++j) {
        const int ct = w * 2 + j;
        half8_t kfe = *reinterpret_cast<const half8_t*>(&woT[(ct * 16 + q) * 40 + g * 8]);
        float4 bb4 = *reinterpret_cast<const float4*>(bo + ct * 16 + g * 4);
#pragma unroll
        for (int rt = 0; rt < 4; ++rt) {
            half8_t qfe = *reinterpret_cast<const half8_t*>(&feat_h[(rt * 16 + q) * 40 + g * 8]);
            f32x4 z = {0.f, 0.f, 0.f, 0.f};
            f32x4 o = MFMA_QK(kfe, qfe, z);
            const size_t base = ((size_t)b * NN + q0 + rt * 16 + q) * CC + ct * 16 + g * 4;
            float4 xv = *reinterpret_cast<const float4*>(x + base);
            float4 ov;
            ov.x = gam * (o[0] + bb4.x) + xv.x;
            ov.y = gam * (o[1] + bb4.y) + xv.y;
            ov.z = gam * (o[2] + bb4.z) + xv.z;
            ov.w = gam * (o[3] + bb4.w) + xv.w;
            *reinterpret_cast<float4*>(out + base) = ov;
        }
    }
}

// ---------------- launch ----------------
extern "C" void kernel_launch(void* const* d_in, const int* in_sizes, int n_in,
                              void* d_out, int out_size, void* d_ws, size_t ws_size,
                              hipStream_t stream) {
    const float* x  = (const float*)d_in[0];
    const float* Wk = (const float*)d_in[1];
    const float* bk = (const float*)d_in[2];
    const float* Wq = (const float*)d_in[3];
    const float* bq = (const float*)d_in[4];
    const float* Wv = (const float*)d_in[5];
    const float* bv = (const float*)d_in[6];
    const float* Wo = (const float*)d_in[7];
    const float* bo = (const float*)d_in[8];
    const float* gamma = (const float*)d_in[9];
    float* out = (float*)d_out;

    half_t* k_ws = (half_t*)d_ws;
    half_t* q_ws = k_ws + (size_t)BB * NN * DD;
    half_t* vT3  = q_ws + (size_t)BB * NN * DD;
    float*  pm   = (float*)(vT3 + (size_t)BB * NN * DD);
    float*  ps   = pm + (size_t)KSPLIT * NROW;
    float*  pO   = ps + (size_t)KSPLIT * NROW;

    proj_kernel<<<256, 512, 0, stream>>>(x, Wk, bk, Wq, bq, Wv, bv, k_ws, q_ws, vT3);
    attn_partial<<<1024, 512, 0, stream>>>(k_ws, q_ws, vT3, pm, ps, pO);
    attn_combine<<<256, 512, 0, stream>>>(pm, ps, pO, x, Wo, bo, gamma, out);
}